// Round 17
// baseline (213.140 us; speedup 1.0000x reference)
//
#include <hip/hip_runtime.h>
#include <hip/hip_bf16.h>

#define BS 8
#define NP 2048
#define CIN 128
#define OC 128
#define NSUP 3
#define KNN 16
#define NC 512   // (NSUP+1)*OC
#define SC 384   // NSUP*OC
#define CAND 24  // candidate depth; distributed as 3 entries x 8 sub-lanes

typedef __attribute__((ext_vector_type(8))) short bf16x8;
typedef __attribute__((ext_vector_type(4))) float f32x4;

__device__ inline unsigned short f2bf(float x) {
    __hip_bfloat16 h = __float2bfloat16(x);
    return *reinterpret_cast<unsigned short*>(&h);
}
__device__ inline float bf2f(short s) {
    unsigned u = ((unsigned)(unsigned short)s) << 16;
    return __uint_as_float(u);
}
__device__ inline unsigned fkey(float d, int gi) {
    unsigned u = __float_as_uint(d);
    u ^= (unsigned)((int)u >> 31) | 0x80000000u;
    return (u & 0xFFFFF800u) | (unsigned)gi;
}
__device__ inline unsigned umn(unsigned a, unsigned b) { return a < b ? a : b; }
__device__ inline unsigned umx(unsigned a, unsigned b) { return a > b ? a : b; }
__device__ inline void cswap(unsigned& a, unsigned& b) {
    unsigned t = umn(a, b); b = umx(a, b); a = t;
}
__device__ inline unsigned dpp_prev(unsigned v) {
    return (unsigned)__builtin_amdgcn_update_dpp(0, (int)v, 0x111, 0xF, 0xF, true);
}
__device__ inline unsigned third_smallest8(const unsigned kv[8]) {
    unsigned s0=kv[0],s1=kv[1],s2=kv[2],s3=kv[3],s4=kv[4],s5=kv[5],s6=kv[6],s7=kv[7];
    cswap(s0,s1); cswap(s2,s3); cswap(s4,s5); cswap(s6,s7);
    cswap(s0,s2); cswap(s1,s3); cswap(s4,s6); cswap(s5,s7);
    cswap(s1,s2); cswap(s5,s6); cswap(s0,s4); cswap(s3,s7);
    cswap(s1,s5); cswap(s2,s6);
    cswap(s1,s4); cswap(s3,s6);
    cswap(s2,s4); cswap(s3,s5);
    cswap(s3,s4);
    return s2;
}

// ---------- 1: fused {sq + bf16 copy}, {weight prep}, {sdn normalize} ----------
__global__ __launch_bounds__(256) void prep_kernel(const float* __restrict__ in,
                                                   float* __restrict__ sq,
                                                   short* __restrict__ outp,
                                                   const float* __restrict__ W,
                                                   const float* __restrict__ conv2,
                                                   const float* __restrict__ stew,
                                                   const float* __restrict__ dirs,
                                                   short* __restrict__ Wt,
                                                   short* __restrict__ conv2b,
                                                   short* __restrict__ stewb,
                                                   float4* __restrict__ sdnn4) {
    const int tid = threadIdx.x;
    if (blockIdx.x < 1024) {
        const int row = blockIdx.x * 16 + (tid >> 4);
        const int seg = tid & 15;
        const float* p = in + (size_t)row * CIN + seg * 8;
        float4 f0 = *(const float4*)p;
        float4 f1 = *(const float4*)(p + 4);
        bf16x8 s;
        s[0] = (short)f2bf(f0.x); s[1] = (short)f2bf(f0.y);
        s[2] = (short)f2bf(f0.z); s[3] = (short)f2bf(f0.w);
        s[4] = (short)f2bf(f1.x); s[5] = (short)f2bf(f1.y);
        s[6] = (short)f2bf(f1.z); s[7] = (short)f2bf(f1.w);
        *(bf16x8*)&outp[(size_t)row * CIN + seg * 8] = s;
        float ss = f0.x*f0.x + f0.y*f0.y + f0.z*f0.z + f0.w*f0.w
                 + f1.x*f1.x + f1.y*f1.y + f1.z*f1.z + f1.w*f1.w;
#pragma unroll
        for (int msk = 1; msk <= 8; msk <<= 1) ss += __shfl_xor(ss, msk);
        if (seg == 0) sq[row] = ss;
    } else if (blockIdx.x < 1472) {
        int idx = (blockIdx.x - 1024) * 256 + tid;
        if (idx < NC * CIN) {
            int n = idx >> 7, k = idx & 127;
            Wt[idx] = (short)f2bf(W[(size_t)k * NC + n]);
        } else if (idx < NC * CIN + OC * 2 * OC) {
            int e = idx - NC * CIN;
            conv2b[e] = (short)f2bf(conv2[e]);
        } else {
            int e = idx - NC * CIN - OC * 2 * OC;
            stewb[e] = (short)f2bf(stew[e]);
        }
    } else {
        int m = (blockIdx.x - 1472) * 256 + tid;
        if (m < SC) {
            float d0 = dirs[m], d1 = dirs[SC + m], d2 = dirs[2 * SC + m];
            float nrm = sqrtf(d0 * d0 + d1 * d1 + d2 * d2);
            float den = fmaxf(nrm, 1e-12f);
            sdnn4[m] = make_float4(d0 / den, d1 / den, d2 / den, 0.f);
        }
    }
}

// ---------- 2: FUSED A — {feature KNN pass-1 (LDS/issue)} ∥ {fm GEMM (MFMA/HBM)}
// Block map: [0,512) feat; [512,1536) gemm. Unlike-pipe pairing.
#define TQF 32
#define TPF 64
#define NCHF (NP / TPF)
#define SMEMA 33536
__global__ __launch_bounds__(256) void fusedA_kernel(const short* __restrict__ fbb,
                                                     const float* __restrict__ sqn,
                                                     int* __restrict__ cand,
                                                     const short* __restrict__ Wt,
                                                     const float* __restrict__ bias,
                                                     float* __restrict__ centerf,
                                                     short* __restrict__ supb) {
    __shared__ alignas(16) unsigned char smem[SMEMA];
    const int bx = blockIdx.x;
    const int tid = threadIdx.x;
    const int lane = tid & 63, wid = tid >> 6;

    if (bx < 512) {
        short (*Qb)[128]   = (short (*)[128])smem;
        short (*Pb)[128]   = (short (*)[128])(smem + 8192);
        float* sqP         = (float*)(smem + 24576);
        unsigned (*Ds)[68] = (unsigned (*)[68])(smem + 24832);

        const int b = bx >> 6, q0 = (bx & 63) * TQF;
        const short* fb = fbb + (size_t)b * NP * CIN;

        unsigned l0 = 0xFFFFFFFFu, l1 = 0xFFFFFFFFu, l2 = 0xFFFFFFFFu;
        unsigned T = 0xFFFFFFFFu;
        const int gbase = lane & 56;
        const int sub = lane & 7;

        for (int i = 0; i < 2; ++i) {
            int v = i * 256 + tid, row = v >> 4, g = v & 15;
            *(bf16x8*)&Qb[row][(g ^ (row & 7)) * 8] =
                *(const bf16x8*)&fb[(size_t)(q0 + row) * CIN + g * 8];
        }
        for (int i = 0; i < 4; ++i) {
            int v = i * 256 + tid, row = v >> 4, g = v & 15;
            *(bf16x8*)&Pb[row][(g ^ (row & 7)) * 8] =
                *(const bf16x8*)&fb[(size_t)row * CIN + g * 8];
        }
        if (tid < TPF) sqP[tid] = sqn[b * NP + tid];

        const int qt = wid >> 1, ph = wid & 1;
        const int qsl = tid >> 3;
        const int arow = qt * 16 + (lane & 15), asw = arow & 7;
        const int brow0 = ph * 32 + (lane & 15), brow1 = brow0 + 16;
        const int bsw0 = brow0 & 7, bsw1 = brow1 & 7;
        const int oct = lane >> 4;
        const int qrow = qt * 16 + oct * 4;

        for (int ch = 0; ch < NCHF; ++ch) {
            __syncthreads();
            bf16x8 st0, st1, st2, st3;
            float sq_next = 0.f;
            const int nxt = (ch + 1 < NCHF);
            if (nxt) {
                int p0n = (ch + 1) * TPF;
                { int v = tid;       int row = v>>4, g = v&15; st0 = *(const bf16x8*)&fb[(size_t)(p0n+row)*CIN + g*8]; }
                { int v = 256 + tid; int row = v>>4, g = v&15; st1 = *(const bf16x8*)&fb[(size_t)(p0n+row)*CIN + g*8]; }
                { int v = 512 + tid; int row = v>>4, g = v&15; st2 = *(const bf16x8*)&fb[(size_t)(p0n+row)*CIN + g*8]; }
                { int v = 768 + tid; int row = v>>4, g = v&15; st3 = *(const bf16x8*)&fb[(size_t)(p0n+row)*CIN + g*8]; }
                if (tid < TPF) sq_next = sqn[b * NP + p0n + tid];
            }
            f32x4 acc0 = {0.f,0.f,0.f,0.f}, acc1 = {0.f,0.f,0.f,0.f};
#pragma unroll
            for (int kk = 0; kk < 4; ++kk) {
                int g = kk * 4 + oct;
                bf16x8 av  = *(const bf16x8*)&Qb[arow][(g ^ asw) * 8];
                bf16x8 bv0 = *(const bf16x8*)&Pb[brow0][(g ^ bsw0) * 8];
                bf16x8 bv1 = *(const bf16x8*)&Pb[brow1][(g ^ bsw1) * 8];
                acc0 = __builtin_amdgcn_mfma_f32_16x16x32_bf16(av, bv0, acc0, 0, 0, 0);
                acc1 = __builtin_amdgcn_mfma_f32_16x16x32_bf16(av, bv1, acc1, 0, 0, 0);
            }
            const float sp0 = sqP[brow0], sp1 = sqP[brow1];
            const int pg0 = ch * TPF + brow0, pg1 = ch * TPF + brow1;
#pragma unroll
            for (int r = 0; r < 4; ++r) {
                int qg = q0 + qrow + r;
                unsigned k0 = fkey(sp0 - 2.0f * acc0[r], pg0);
                unsigned k1 = fkey(sp1 - 2.0f * acc1[r], pg1);
                if (qg == pg0) k0 = 0xFFFFFFFFu;
                if (qg == pg1) k1 = 0xFFFFFFFFu;
                Ds[qrow + r][brow0] = k0;
                Ds[qrow + r][brow1] = k1;
            }
            __syncthreads();
            {
                uint4 kA = *(const uint4*)&Ds[qsl][sub * 8];
                uint4 kB = *(const uint4*)&Ds[qsl][sub * 8 + 4];
                unsigned kv[8] = {kA.x, kA.y, kA.z, kA.w, kB.x, kB.y, kB.z, kB.w};
                if (ch == 0) {
                    unsigned m3 = third_smallest8(kv);
                    m3 = umx(m3, (unsigned)__shfl_xor((int)m3, 1));
                    m3 = umx(m3, (unsigned)__shfl_xor((int)m3, 2));
                    m3 = umx(m3, (unsigned)__shfl_xor((int)m3, 4));
                    T = m3 + 1;
                }
#pragma unroll
                for (int j = 0; j < 8; ++j) {
                    unsigned long long bal = __ballot(kv[j] < T);
                    unsigned gm = (unsigned)(bal >> gbase) & 0xFFu;
                    while (gm) {
                        int l = __builtin_ctz(gm);
                        gm &= gm - 1;
                        unsigned k = (unsigned)__shfl((int)kv[j], gbase + l);
                        unsigned pv = dpp_prev(l2);
                        if (sub == 0) pv = 0u;
                        unsigned n0 = umn(umx(pv, k), l0);
                        unsigned n1 = umn(umx(l0, k), l1);
                        unsigned n2 = umn(umx(l1, k), l2);
                        l0 = n0; l1 = n1; l2 = n2;
                    }
                }
                T = (unsigned)__shfl((int)l2, gbase + 7);
            }
            if (nxt) {
                { int v = tid;       int row = v>>4, g = v&15; *(bf16x8*)&Pb[row][(g^(row&7))*8] = st0; }
                { int v = 256 + tid; int row = v>>4, g = v&15; *(bf16x8*)&Pb[row][(g^(row&7))*8] = st1; }
                { int v = 512 + tid; int row = v>>4, g = v&15; *(bf16x8*)&Pb[row][(g^(row&7))*8] = st2; }
                { int v = 768 + tid; int row = v>>4, g = v&15; *(bf16x8*)&Pb[row][(g^(row&7))*8] = st3; }
                if (tid < TPF) sqP[tid] = sq_next;
            }
        }
        {
            int* dst = cand + ((size_t)b * NP + q0 + qsl) * CAND;
            dst[3 * sub + 0] = (int)(l0 & 0x7FFu);
            dst[3 * sub + 1] = (int)(l1 & 0x7FFu);
            dst[3 * sub + 2] = (int)(l2 & 0x7FFu);
        }
    } else {
        // ===== fm GEMM — bf16 MFMA; center->fp32, support->bf16 =====
        short (*As)[128] = (short (*)[128])smem;
        const int bb = bx - 512;
        const int m0 = (bb & 255) * 64, n0 = (bb >> 8) * 128;
        const int oct = lane >> 4;
        for (int i = 0; i < 4; ++i) {
            int v = i * 256 + tid, row = v >> 4, g = v & 15;
            *(bf16x8*)&As[row][(g ^ (row & 7)) * 8] =
                *(const bf16x8*)&fbb[(size_t)(m0 + row) * CIN + g * 8];
        }
        __syncthreads();
        f32x4 acc[4][2] = {};
#pragma unroll
        for (int kk = 0; kk < 4; ++kk) {
            int g = kk * 4 + oct;
            bf16x8 bv[2];
#pragma unroll
            for (int nt = 0; nt < 2; ++nt) {
                int n = n0 + (wid * 2 + nt) * 16 + (lane & 15);
                bv[nt] = *(const bf16x8*)&Wt[(size_t)n * CIN + g * 8];
            }
#pragma unroll
            for (int mt = 0; mt < 4; ++mt) {
                int ar = mt * 16 + (lane & 15);
                bf16x8 av = *(const bf16x8*)&As[ar][(g ^ (ar & 7)) * 8];
#pragma unroll
                for (int nt = 0; nt < 2; ++nt)
                    acc[mt][nt] = __builtin_amdgcn_mfma_f32_16x16x32_bf16(av, bv[nt], acc[mt][nt], 0, 0, 0);
            }
        }
#pragma unroll
        for (int mt = 0; mt < 4; ++mt)
#pragma unroll
            for (int nt = 0; nt < 2; ++nt) {
                int n = n0 + (wid * 2 + nt) * 16 + (lane & 15);
                float bsv = bias[n];
                int mbase = m0 + mt * 16 + oct * 4;
#pragma unroll
                for (int r = 0; r < 4; ++r) {
                    float val = acc[mt][nt][r] + bsv;
                    if (n0 == 0)
                        centerf[(size_t)(mbase + r) * OC + n] = val;
                    else
                        supb[(size_t)(mbase + r) * SC + (n - OC)] = (short)f2bf(val);
                }
            }
    }
}

// ---------- 3: FUSED B — {refine: 8-cand-parallel} ∥ {vertex KNN} ----------
// Refine: wave = 1 query; 8 groups x 8 lanes; 16 dims/lane; 3 serial iters.
// fp64 inner (2 indep 8-FMA chains), REFERENCE fp32 rounding chain preserved:
// d32 = fl32( fl32(sq_i + sq_j) - fl32(2*dot) ). (d32,idx) u64 rank unchanged.
// Block map: [0,4096) refine; [4096,4608) vert.
#define SMEMB 24576
__global__ __launch_bounds__(256) void fusedB_kernel(const float* __restrict__ feat,
                                                     const int* __restrict__ cand,
                                                     int* __restrict__ nbr,
                                                     const float* __restrict__ vert,
                                                     int* __restrict__ nbr2) {
    __shared__ alignas(16) unsigned char smem[SMEMB];
    const int bx = blockIdx.x;
    const int tid = threadIdx.x;
    const int lane = tid & 63, wid = tid >> 6;

    if (bx < 4096) {
        unsigned long long (*keyS)[CAND] = (unsigned long long (*)[CAND])smem;
        const int w = wid;
        const int gc = lane >> 3, sl = lane & 7;   // candidate group, dim chunk
        const int gq = bx * 4 + w;
        const int b = gq >> 11;
        const int q = gq & (NP - 1);
        const float* fb = feat + (size_t)b * NP * CIN;

        float qf[16];
        *(float4*)&qf[0]  = *(const float4*)&fb[(size_t)q * CIN + sl * 16 + 0];
        *(float4*)&qf[4]  = *(const float4*)&fb[(size_t)q * CIN + sl * 16 + 4];
        *(float4*)&qf[8]  = *(const float4*)&fb[(size_t)q * CIN + sl * 16 + 8];
        *(float4*)&qf[12] = *(const float4*)&fb[(size_t)q * CIN + sl * 16 + 12];
        double sa = 0.0, sb = 0.0;
#pragma unroll
        for (int i = 0; i < 8; ++i) {
            sa += (double)qf[i] * (double)qf[i];
            sb += (double)qf[8 + i] * (double)qf[8 + i];
        }
        double sqd = sa + sb;
#pragma unroll
        for (int msk = 1; msk <= 4; msk <<= 1) sqd += __shfl_xor(sqd, msk);
        const float sqi = (float)sqd;

        const int* cq = cand + (size_t)gq * CAND;
        int jv[3];
#pragma unroll
        for (int t = 0; t < 3; ++t) jv[t] = cq[t * 8 + gc];

#pragma unroll
        for (int t = 0; t < 3; ++t) {
            const int j = jv[t];
            float cf[16];
            *(float4*)&cf[0]  = *(const float4*)&fb[(size_t)j * CIN + sl * 16 + 0];
            *(float4*)&cf[4]  = *(const float4*)&fb[(size_t)j * CIN + sl * 16 + 4];
            *(float4*)&cf[8]  = *(const float4*)&fb[(size_t)j * CIN + sl * 16 + 8];
            *(float4*)&cf[12] = *(const float4*)&fb[(size_t)j * CIN + sl * 16 + 12];
            double d0 = 0.0, d1 = 0.0, e0 = 0.0, e1 = 0.0;
#pragma unroll
            for (int i = 0; i < 8; ++i) {
                d0 += (double)qf[i] * (double)cf[i];
                e0 += (double)cf[i] * (double)cf[i];
                d1 += (double)qf[8 + i] * (double)cf[8 + i];
                e1 += (double)cf[8 + i] * (double)cf[8 + i];
            }
            double dot = d0 + d1, sj = e0 + e1;
#pragma unroll
            for (int msk = 1; msk <= 4; msk <<= 1) {
                dot += __shfl_xor(dot, msk);
                sj  += __shfl_xor(sj, msk);
            }
            if (sl == 0) {
                float t1 = sqi + (float)sj;
                float t2 = (float)(2.0 * dot);
                float d32 = t1 - t2;
                unsigned u = __float_as_uint(d32);
                u ^= (unsigned)((int)u >> 31) | 0x80000000u;
                keyS[w][t * 8 + gc] = ((unsigned long long)u << 32) | (unsigned)j;
            }
        }
        __syncthreads();
        if (lane < CAND) {
            unsigned long long k = keyS[w][lane];
            int rank = 0;
#pragma unroll
            for (int m = 0; m < CAND; ++m) rank += (keyS[w][m] < k) ? 1 : 0;
            if (rank < KNN) nbr[(size_t)gq * KNN + rank] = (int)(k & 0xFFFFFFFFu);
        }
    } else {
        // ===== vertex KNN — distributed top-24 (DPP) =====
        float* vx = (float*)smem;
        float* vy = (float*)(smem + 8192);
        float* vz = (float*)(smem + 16384);
        const int bb = bx - 4096;
        const int b = bb >> 6, q0 = (bb & 63) * 32;
        const float* vb = vert + (size_t)b * NP * 3;

        for (int i = 0; i < NP * 3 / 256; ++i) {
            int e = i * 256 + tid;
            float v = vb[e];
            int row = e / 3, comp = e % 3;
            (comp == 0 ? vx : comp == 1 ? vy : vz)[row] = v;
        }
        __syncthreads();

        const int gbase = lane & 56;
        const int q = tid >> 3;
        const int sub = tid & 7;
        const float qx = vx[q0 + q], qy = vy[q0 + q], qz = vz[q0 + q];

        unsigned l0 = 0xFFFFFFFFu, l1 = 0xFFFFFFFFu, l2 = 0xFFFFFFFFu;
        unsigned T = 0xFFFFFFFFu;

        for (int m = 0; m < NP / 64; ++m) {
            const int p0 = m * 64 + sub * 8;
            float4 xA = *(const float4*)&vx[p0], xB = *(const float4*)&vx[p0 + 4];
            float4 yA = *(const float4*)&vy[p0], yB = *(const float4*)&vy[p0 + 4];
            float4 zA = *(const float4*)&vz[p0], zB = *(const float4*)&vz[p0 + 4];
            float dv[8];
            { float dx = qx-xA.x, dy = qy-yA.x, dz = qz-zA.x; dv[0] = dx*dx+dy*dy+dz*dz; }
            { float dx = qx-xA.y, dy = qy-yA.y, dz = qz-zA.y; dv[1] = dx*dx+dy*dy+dz*dz; }
            { float dx = qx-xA.z, dy = qy-yA.z, dz = qz-zA.z; dv[2] = dx*dx+dy*dy+dz*dz; }
            { float dx = qx-xA.w, dy = qy-yA.w, dz = qz-zA.w; dv[3] = dx*dx+dy*dy+dz*dz; }
            { float dx = qx-xB.x, dy = qy-yB.x, dz = qz-zB.x; dv[4] = dx*dx+dy*dy+dz*dz; }
            { float dx = qx-xB.y, dy = qy-yB.y, dz = qz-zB.y; dv[5] = dx*dx+dy*dy+dz*dz; }
            { float dx = qx-xB.z, dy = qy-yB.z, dz = qz-zB.z; dv[6] = dx*dx+dy*dy+dz*dz; }
            { float dx = qx-xB.w, dy = qy-yB.w, dz = qz-zB.w; dv[7] = dx*dx+dy*dy+dz*dz; }
            unsigned kv[8];
#pragma unroll
            for (int j = 0; j < 8; ++j) kv[j] = fkey(dv[j], p0 + j);
            if (m == 0) {
                unsigned m3 = third_smallest8(kv);
                m3 = umx(m3, (unsigned)__shfl_xor((int)m3, 1));
                m3 = umx(m3, (unsigned)__shfl_xor((int)m3, 2));
                m3 = umx(m3, (unsigned)__shfl_xor((int)m3, 4));
                T = m3 + 1;
            }
#pragma unroll
            for (int j = 0; j < 8; ++j) {
                unsigned long long bal = __ballot(kv[j] < T);
                unsigned gm = (unsigned)(bal >> gbase) & 0xFFu;
                while (gm) {
                    int l = __builtin_ctz(gm);
                    gm &= gm - 1;
                    unsigned k = (unsigned)__shfl((int)kv[j], gbase + l);
                    unsigned pv = dpp_prev(l2);
                    if (sub == 0) pv = 0u;
                    unsigned n0 = umn(umx(pv, k), l0);
                    unsigned n1 = umn(umx(l0, k), l1);
                    unsigned n2 = umn(umx(l1, k), l2);
                    l0 = n0; l1 = n1; l2 = n2;
                }
            }
            T = (unsigned)__shfl((int)l2, gbase + 7);
        }
        {
            int* dst = nbr2 + ((size_t)b * NP + q0 + q) * KNN;
            unsigned vals[3] = {l0, l1, l2};
#pragma unroll
            for (int e = 0; e < 3; ++e) {
                int r = 3 * sub + e;
                if (r >= 1 && r <= 16) dst[r - 1] = (int)(vals[e] & 0x7FFu);
            }
        }
    }
}

// ---------- 5: activation — bf16 support gathers + center + bf16 copy ----------
__global__ __launch_bounds__(128) void act_kernel(const float* __restrict__ centerf,
                                                  const short* __restrict__ supb,
                                                  const int* __restrict__ nbr,
                                                  const float* __restrict__ vert,
                                                  const float4* __restrict__ sdnn4,
                                                  float* __restrict__ feature,
                                                  short* __restrict__ featb) {
    __shared__ int sj[KNN];
    __shared__ float rf[KNN][4];
    const int i = blockIdx.x;
    const int b = blockIdx.y;
    const int tid = threadIdx.x;
    const size_t bi = (size_t)b * NP + i;
    if (tid < KNN) {
        int j = nbr[bi * KNN + tid];
        sj[tid] = j;
        const float* vb = vert + (size_t)b * NP * 3;
        float dx = vb[j * 3 + 0] - vb[i * 3 + 0];
        float dy = vb[j * 3 + 1] - vb[i * 3 + 1];
        float dz = vb[j * 3 + 2] - vb[i * 3 + 2];
        float nrm = sqrtf(dx * dx + dy * dy + dz * dz);
        float den = fmaxf(nrm, 1e-12f);
        rf[tid][0] = dx / den; rf[tid][1] = dy / den; rf[tid][2] = dz / den;
    }
    __syncthreads();
    const int oc = tid;
    float accm = 0.0f;
#pragma unroll
    for (int s = 0; s < NSUP; ++s) {
        int m = s * OC + oc;
        float4 sv = sdnn4[m];
        float s0 = sv.x, s1 = sv.y, s2 = sv.z;
        float vm[4] = {-3.0e38f, -3.0e38f, -3.0e38f, -3.0e38f};
#pragma unroll
        for (int kk = 0; kk < KNN; ++kk) {
            float th = fmaxf(rf[kk][0] * s0 + rf[kk][1] * s1 + rf[kk][2] * s2, 0.0f);
            float sup = bf2f(supb[((size_t)b * NP + sj[kk]) * SC + m]);
            vm[kk & 3] = fmaxf(vm[kk & 3], th * sup);
        }
        accm += fmaxf(fmaxf(vm[0], vm[1]), fmaxf(vm[2], vm[3]));
    }
    float v = centerf[bi * OC + oc] + accm / 3.0f;
    feature[bi * OC + oc] = v;
    featb[bi * OC + oc] = (short)f2bf(v);
}

// ---------- 6: neighborhood max-pool (bf16 featb gathers) ----------
__global__ __launch_bounds__(128) void pool_kernel(const short* __restrict__ featb,
                                                   const int* __restrict__ nbr2,
                                                   float* __restrict__ pooled) {
    __shared__ int sj[KNN];
    const int i = blockIdx.x, b = blockIdx.y, tid = threadIdx.x;
    const size_t bi = (size_t)b * NP + i;
    if (tid < KNN) sj[tid] = nbr2[bi * KNN + tid];
    __syncthreads();
    float m0 = -3.0e38f, m1 = -3.0e38f, m2 = -3.0e38f, m3 = -3.0e38f;
#pragma unroll
    for (int kk = 0; kk < KNN; kk += 4) {
        m0 = fmaxf(m0, bf2f(featb[((size_t)b * NP + sj[kk + 0]) * OC + tid]));
        m1 = fmaxf(m1, bf2f(featb[((size_t)b * NP + sj[kk + 1]) * OC + tid]));
        m2 = fmaxf(m2, bf2f(featb[((size_t)b * NP + sj[kk + 2]) * OC + tid]));
        m3 = fmaxf(m3, bf2f(featb[((size_t)b * NP + sj[kk + 3]) * OC + tid]));
    }
    pooled[bi * OC + tid] = fmaxf(fmaxf(m0, m1), fmaxf(m2, m3));
}

// ---------- 7a: partial sums of pooled over N ----------
__global__ __launch_bounds__(128) void partial_kernel(const float* __restrict__ pooled,
                                                      float* __restrict__ part) {
    const int ch = blockIdx.x, b = blockIdx.y, tid = threadIdx.x;
    float s0 = 0.f, s1 = 0.f, s2 = 0.f, s3 = 0.f;
    const float* base = pooled + ((size_t)b * NP + ch * 128) * OC + tid;
    for (int i = 0; i < 128; i += 4) {
        s0 += base[(size_t)(i + 0) * OC];
        s1 += base[(size_t)(i + 1) * OC];
        s2 += base[(size_t)(i + 2) * OC];
        s3 += base[(size_t)(i + 3) * OC];
    }
    part[((size_t)b * 16 + ch) * OC + tid] = ((s0 + s1) + (s2 + s3));
}
// ---------- 7b: fused fglob + gdot ----------
__global__ __launch_bounds__(128) void fg_gdot_kernel(const float* __restrict__ part,
                                                      const float* __restrict__ conv2,
                                                      float* __restrict__ gd) {
    __shared__ float fgs[OC];
    const int b = blockIdx.x, tid = threadIdx.x;
    float s = 0.f;
#pragma unroll
    for (int c = 0; c < 16; ++c) s += part[((size_t)b * 16 + c) * OC + tid];
    fgs[tid] = s / (float)NP;
    __syncthreads();
    float g = 0.f;
    const float* w = conv2 + (size_t)tid * 2 * OC + OC;
    for (int c = 0; c < OC; ++c) g += fgs[c] * w[c];
    gd[b * OC + tid] = g;
}

// ---------- 8: final — bf16 MFMA conv2(feat) + ste(fmap) + gd + residual ----------
__global__ __launch_bounds__(256) void final_kernel(const short* __restrict__ featb,
                                                    const short* __restrict__ fbb,
                                                    const short* __restrict__ conv2b,
                                                    const short* __restrict__ stewb,
                                                    const float* __restrict__ gd,
                                                    const float* __restrict__ feature,
                                                    float* __restrict__ out) {
    __shared__ alignas(16) short Af[32][128];
    __shared__ alignas(16) short Am[32][128];
    const int m0 = blockIdx.x * 32, tid = threadIdx.x;
    const int lane = tid & 63, wid = tid >> 6, oct = lane >> 4;
    for (int i = 0; i < 2; ++i) {
        int v = i * 256 + tid, row = v >> 4, g = v & 15;
        *(bf16x8*)&Af[row][(g ^ (row & 7)) * 8] =
            *(const bf16x8*)&featb[(size_t)(m0 + row) * OC + g * 8];
        *(bf16x8*)&Am[row][(g ^ (row & 7)) * 8] =
            *(const bf16x8*)&fbb[(size_t)(m0 + row) * CIN + g * 8];
    }
    __syncthreads();
    f32x4 acc[2][2] = {};
#pragma unroll
    for (int kk = 0; kk < 4; ++kk) {
        int g = kk * 4 + oct;
        bf16x8 bC[2], bS[2];
#pragma unroll
        for (int nt = 0; nt < 2; ++nt) {
            int n = (wid * 2 + nt) * 16 + (lane & 15);
            bC[nt] = *(const bf16x8*)&conv2b[(size_t)n * (2 * OC) + g * 8];
            bS[nt] = *(const bf16x8*)&stewb[(size_t)n * CIN + g * 8];
        }
#pragma unroll
        for (int mt = 0; mt < 2; ++mt) {
            int ar = mt * 16 + (lane & 15);
            bf16x8 aF = *(const bf16x8*)&Af[ar][(g ^ (ar & 7)) * 8];
            bf16x8 aM = *(const bf16x8*)&Am[ar][(g ^ (ar & 7)) * 8];
#pragma unroll
            for (int nt = 0; nt < 2; ++nt) {
                acc[mt][nt] = __builtin_amdgcn_mfma_f32_16x16x32_bf16(aF, bC[nt], acc[mt][nt], 0, 0, 0);
                acc[mt][nt] = __builtin_amdgcn_mfma_f32_16x16x32_bf16(aM, bS[nt], acc[mt][nt], 0, 0, 0);
            }
        }
    }
#pragma unroll
    for (int mt = 0; mt < 2; ++mt)
#pragma unroll
        for (int nt = 0; nt < 2; ++nt) {
            int o = (wid * 2 + nt) * 16 + (lane & 15);
            int mbase = m0 + mt * 16 + oct * 4;
#pragma unroll
            for (int r = 0; r < 4; ++r) {
                int m = mbase + r;
                out[(size_t)m * OC + o] = acc[mt][nt][r]
                    + gd[(m >> 11) * OC + o] + feature[(size_t)m * OC + o];
            }
        }
}

extern "C" void kernel_launch(void* const* d_in, const int* in_sizes, int n_in,
                              void* d_out, int out_size, void* d_ws, size_t ws_size,
                              hipStream_t stream) {
    const float* vert  = (const float*)d_in[0];
    const float* fmap  = (const float*)d_in[1];
    const float* W     = (const float*)d_in[2];
    const float* bias  = (const float*)d_in[3];
    const float* dirs  = (const float*)d_in[4];
    const float* stew  = (const float*)d_in[5];
    const float* conv2 = (const float*)d_in[6];
    float* out = (float*)d_out;

    float* ws      = (float*)d_ws;
    float* sqn     = ws;                             // 16384
    short* fbb     = (short*)(sqn + 16384);          // 2M shorts
    float* centerf = sqn + 16384 + 1048576;          // 2M floats
    short* supb    = (short*)(centerf + 2097152);    // 6.29M shorts
    float* feature = centerf + 2097152 + 3145728;    // 2M floats
    short* featb   = (short*)(feature + 2097152);    // 2M shorts
    float* gd      = feature + 2097152 + 1048576;    // 1024
    short* Wt      = (short*)(gd + 1024);            // 65536 shorts
    short* conv2b  = Wt + 65536;                     // 32768 shorts
    short* stewb   = conv2b + 32768;                 // 16384 shorts
    int*   nbr1    = (int*)(stewb + 16384);          // 262144
    int*   nbr2    = nbr1 + 262144;                  // 262144
    float* part    = (float*)(nbr2 + 262144);        // 16384
    float4* sdnn4  = (float4*)(part + 16384);        // 384 float4
    int*   cand    = (int*)(sdnn4 + 384);            // 393216
    float* pooled  = (float*)(cand + 393216);        // 2M floats

    prep_kernel<<<1474, 256, 0, stream>>>(fmap, sqn, fbb, W, conv2, stew, dirs,
                                          Wt, conv2b, stewb, sdnn4);
    fusedA_kernel<<<1536, 256, 0, stream>>>(fbb, sqn, cand, Wt, bias, centerf, supb);
    fusedB_kernel<<<4608, 256, 0, stream>>>(fmap, cand, nbr1, vert, nbr2);
    act_kernel<<<dim3(2048, 8), 128, 0, stream>>>(centerf, supb, nbr1, vert, sdnn4,
                                                  feature, featb);
    pool_kernel<<<dim3(2048, 8), 128, 0, stream>>>(featb, nbr2, pooled);
    partial_kernel<<<dim3(16, 8), 128, 0, stream>>>(pooled, part);
    fg_gdot_kernel<<<8, 128, 0, stream>>>(part, conv2, gd);
    final_kernel<<<512, 256, 0, stream>>>(featb, fbb, conv2b, stewb, gd, feature, out);
}

// Round 18
// 205.758 us; speedup vs baseline: 1.0359x; 1.0359x over previous
//
#include <hip/hip_runtime.h>
#include <hip/hip_bf16.h>

#define BS 8
#define NP 2048
#define CIN 128
#define OC 128
#define NSUP 3
#define KNN 16
#define NC 512   // (NSUP+1)*OC
#define SC 384   // NSUP*OC
#define CAND 24  // candidate depth; distributed as 3 entries x 8 sub-lanes

typedef __attribute__((ext_vector_type(8))) short bf16x8;
typedef __attribute__((ext_vector_type(4))) float f32x4;

__device__ inline unsigned short f2bf(float x) {
    __hip_bfloat16 h = __float2bfloat16(x);
    return *reinterpret_cast<unsigned short*>(&h);
}
__device__ inline float bf2f(short s) {
    unsigned u = ((unsigned)(unsigned short)s) << 16;
    return __uint_as_float(u);
}
__device__ inline unsigned fkey(float d, int gi) {
    unsigned u = __float_as_uint(d);
    u ^= (unsigned)((int)u >> 31) | 0x80000000u;
    return (u & 0xFFFFF800u) | (unsigned)gi;
}
__device__ inline unsigned umn(unsigned a, unsigned b) { return a < b ? a : b; }
__device__ inline unsigned umx(unsigned a, unsigned b) { return a > b ? a : b; }
__device__ inline void cswap(unsigned& a, unsigned& b) {
    unsigned t = umn(a, b); b = umx(a, b); a = t;
}
__device__ inline unsigned dpp_prev(unsigned v) {
    return (unsigned)__builtin_amdgcn_update_dpp(0, (int)v, 0x111, 0xF, 0xF, true);
}
__device__ inline unsigned third_smallest8(const unsigned kv[8]) {
    unsigned s0=kv[0],s1=kv[1],s2=kv[2],s3=kv[3],s4=kv[4],s5=kv[5],s6=kv[6],s7=kv[7];
    cswap(s0,s1); cswap(s2,s3); cswap(s4,s5); cswap(s6,s7);
    cswap(s0,s2); cswap(s1,s3); cswap(s4,s6); cswap(s5,s7);
    cswap(s1,s2); cswap(s5,s6); cswap(s0,s4); cswap(s3,s7);
    cswap(s1,s5); cswap(s2,s6);
    cswap(s1,s4); cswap(s3,s6);
    cswap(s2,s4); cswap(s3,s5);
    cswap(s3,s4);
    return s2;
}

// ---------- 1: fused {sq + bf16 copy}, {weight prep}, {sdn normalize} ----------
__global__ __launch_bounds__(256) void prep_kernel(const float* __restrict__ in,
                                                   float* __restrict__ sq,
                                                   short* __restrict__ outp,
                                                   const float* __restrict__ W,
                                                   const float* __restrict__ conv2,
                                                   const float* __restrict__ stew,
                                                   const float* __restrict__ dirs,
                                                   short* __restrict__ Wt,
                                                   short* __restrict__ conv2b,
                                                   short* __restrict__ stewb,
                                                   float4* __restrict__ sdnn4) {
    const int tid = threadIdx.x;
    if (blockIdx.x < 1024) {                       // sqbf part
        const int row = blockIdx.x * 16 + (tid >> 4);
        const int seg = tid & 15;
        const float* p = in + (size_t)row * CIN + seg * 8;
        float4 f0 = *(const float4*)p;
        float4 f1 = *(const float4*)(p + 4);
        bf16x8 s;
        s[0] = (short)f2bf(f0.x); s[1] = (short)f2bf(f0.y);
        s[2] = (short)f2bf(f0.z); s[3] = (short)f2bf(f0.w);
        s[4] = (short)f2bf(f1.x); s[5] = (short)f2bf(f1.y);
        s[6] = (short)f2bf(f1.z); s[7] = (short)f2bf(f1.w);
        *(bf16x8*)&outp[(size_t)row * CIN + seg * 8] = s;
        float ss = f0.x*f0.x + f0.y*f0.y + f0.z*f0.z + f0.w*f0.w
                 + f1.x*f1.x + f1.y*f1.y + f1.z*f1.z + f1.w*f1.w;
#pragma unroll
        for (int msk = 1; msk <= 8; msk <<= 1) ss += __shfl_xor(ss, msk);
        if (seg == 0) sq[row] = ss;
    } else if (blockIdx.x < 1472) {                // wprep part
        int idx = (blockIdx.x - 1024) * 256 + tid;
        if (idx < NC * CIN) {
            int n = idx >> 7, k = idx & 127;
            Wt[idx] = (short)f2bf(W[(size_t)k * NC + n]);
        } else if (idx < NC * CIN + OC * 2 * OC) {
            int e = idx - NC * CIN;
            conv2b[e] = (short)f2bf(conv2[e]);
        } else {
            int e = idx - NC * CIN - OC * 2 * OC;
            stewb[e] = (short)f2bf(stew[e]);
        }
    } else {                                       // sdn normalize
        int m = (blockIdx.x - 1472) * 256 + tid;
        if (m < SC) {
            float d0 = dirs[m], d1 = dirs[SC + m], d2 = dirs[2 * SC + m];
            float nrm = sqrtf(d0 * d0 + d1 * d1 + d2 * d2);
            float den = fmaxf(nrm, 1e-12f);
            sdnn4[m] = make_float4(d0 / den, d1 / den, d2 / den, 0.f);
        }
    }
}

// ---------- 2: FUSED {feature KNN pass-1, vertex KNN, fm GEMM} ----------
// Block map: [0,512) feat; [512,1024) vert; [1024,2048) gemm.
#define TQF 32
#define TPF 64
#define NCHF (NP / TPF)
#define SMEM_BYTES 33536
__global__ __launch_bounds__(256) void fused_kernel(const short* __restrict__ fbb,
                                                    const float* __restrict__ sqn,
                                                    int* __restrict__ cand,
                                                    const float* __restrict__ vert,
                                                    int* __restrict__ nbr2,
                                                    const short* __restrict__ Wt,
                                                    const float* __restrict__ bias,
                                                    float* __restrict__ centerf,
                                                    short* __restrict__ supb) {
    __shared__ alignas(16) unsigned char smem[SMEM_BYTES];
    const int bx = blockIdx.x;
    const int tid = threadIdx.x;
    const int lane = tid & 63, wid = tid >> 6;

    if (bx < 512) {
        // ===== feature KNN pass 1 — MFMA Gram + distributed top-24 =====
        short (*Qb)[128]   = (short (*)[128])smem;                    //  8192
        short (*Pb)[128]   = (short (*)[128])(smem + 8192);           // 16384
        float* sqP         = (float*)(smem + 24576);                  //   256
        unsigned (*Ds)[68] = (unsigned (*)[68])(smem + 24832);        //  8704

        const int b = bx >> 6, q0 = (bx & 63) * TQF;
        const short* fb = fbb + (size_t)b * NP * CIN;

        unsigned l0 = 0xFFFFFFFFu, l1 = 0xFFFFFFFFu, l2 = 0xFFFFFFFFu;
        unsigned T = 0xFFFFFFFFu;
        const int gbase = lane & 56;
        const int sub = lane & 7;

        for (int i = 0; i < 2; ++i) {
            int v = i * 256 + tid, row = v >> 4, g = v & 15;
            *(bf16x8*)&Qb[row][(g ^ (row & 7)) * 8] =
                *(const bf16x8*)&fb[(size_t)(q0 + row) * CIN + g * 8];
        }
        for (int i = 0; i < 4; ++i) {
            int v = i * 256 + tid, row = v >> 4, g = v & 15;
            *(bf16x8*)&Pb[row][(g ^ (row & 7)) * 8] =
                *(const bf16x8*)&fb[(size_t)row * CIN + g * 8];
        }
        if (tid < TPF) sqP[tid] = sqn[b * NP + tid];

        const int qt = wid >> 1, ph = wid & 1;
        const int qsl = tid >> 3;
        const int arow = qt * 16 + (lane & 15), asw = arow & 7;
        const int brow0 = ph * 32 + (lane & 15), brow1 = brow0 + 16;
        const int bsw0 = brow0 & 7, bsw1 = brow1 & 7;
        const int oct = lane >> 4;
        const int qrow = qt * 16 + oct * 4;

        for (int ch = 0; ch < NCHF; ++ch) {
            __syncthreads();
            bf16x8 st0, st1, st2, st3;
            float sq_next = 0.f;
            const int nxt = (ch + 1 < NCHF);
            if (nxt) {
                int p0n = (ch + 1) * TPF;
                { int v = tid;       int row = v>>4, g = v&15; st0 = *(const bf16x8*)&fb[(size_t)(p0n+row)*CIN + g*8]; }
                { int v = 256 + tid; int row = v>>4, g = v&15; st1 = *(const bf16x8*)&fb[(size_t)(p0n+row)*CIN + g*8]; }
                { int v = 512 + tid; int row = v>>4, g = v&15; st2 = *(const bf16x8*)&fb[(size_t)(p0n+row)*CIN + g*8]; }
                { int v = 768 + tid; int row = v>>4, g = v&15; st3 = *(const bf16x8*)&fb[(size_t)(p0n+row)*CIN + g*8]; }
                if (tid < TPF) sq_next = sqn[b * NP + p0n + tid];
            }
            f32x4 acc0 = {0.f,0.f,0.f,0.f}, acc1 = {0.f,0.f,0.f,0.f};
#pragma unroll
            for (int kk = 0; kk < 4; ++kk) {
                int g = kk * 4 + oct;
                bf16x8 av  = *(const bf16x8*)&Qb[arow][(g ^ asw) * 8];
                bf16x8 bv0 = *(const bf16x8*)&Pb[brow0][(g ^ bsw0) * 8];
                bf16x8 bv1 = *(const bf16x8*)&Pb[brow1][(g ^ bsw1) * 8];
                acc0 = __builtin_amdgcn_mfma_f32_16x16x32_bf16(av, bv0, acc0, 0, 0, 0);
                acc1 = __builtin_amdgcn_mfma_f32_16x16x32_bf16(av, bv1, acc1, 0, 0, 0);
            }
            const float sp0 = sqP[brow0], sp1 = sqP[brow1];
            const int pg0 = ch * TPF + brow0, pg1 = ch * TPF + brow1;
#pragma unroll
            for (int r = 0; r < 4; ++r) {
                int qg = q0 + qrow + r;
                unsigned k0 = fkey(sp0 - 2.0f * acc0[r], pg0);
                unsigned k1 = fkey(sp1 - 2.0f * acc1[r], pg1);
                if (qg == pg0) k0 = 0xFFFFFFFFu;
                if (qg == pg1) k1 = 0xFFFFFFFFu;
                Ds[qrow + r][brow0] = k0;
                Ds[qrow + r][brow1] = k1;
            }
            __syncthreads();
            {
                uint4 kA = *(const uint4*)&Ds[qsl][sub * 8];
                uint4 kB = *(const uint4*)&Ds[qsl][sub * 8 + 4];
                unsigned kv[8] = {kA.x, kA.y, kA.z, kA.w, kB.x, kB.y, kB.z, kB.w};
                if (ch == 0) {
                    unsigned m3 = third_smallest8(kv);
                    m3 = umx(m3, (unsigned)__shfl_xor((int)m3, 1));
                    m3 = umx(m3, (unsigned)__shfl_xor((int)m3, 2));
                    m3 = umx(m3, (unsigned)__shfl_xor((int)m3, 4));
                    T = m3 + 1;
                }
#pragma unroll
                for (int j = 0; j < 8; ++j) {
                    unsigned long long bal = __ballot(kv[j] < T);
                    unsigned gm = (unsigned)(bal >> gbase) & 0xFFu;
                    while (gm) {
                        int l = __builtin_ctz(gm);
                        gm &= gm - 1;
                        unsigned k = (unsigned)__shfl((int)kv[j], gbase + l);
                        unsigned pv = dpp_prev(l2);
                        if (sub == 0) pv = 0u;
                        unsigned n0 = umn(umx(pv, k), l0);
                        unsigned n1 = umn(umx(l0, k), l1);
                        unsigned n2 = umn(umx(l1, k), l2);
                        l0 = n0; l1 = n1; l2 = n2;
                    }
                }
                T = (unsigned)__shfl((int)l2, gbase + 7);
            }
            if (nxt) {
                { int v = tid;       int row = v>>4, g = v&15; *(bf16x8*)&Pb[row][(g^(row&7))*8] = st0; }
                { int v = 256 + tid; int row = v>>4, g = v&15; *(bf16x8*)&Pb[row][(g^(row&7))*8] = st1; }
                { int v = 512 + tid; int row = v>>4, g = v&15; *(bf16x8*)&Pb[row][(g^(row&7))*8] = st2; }
                { int v = 768 + tid; int row = v>>4, g = v&15; *(bf16x8*)&Pb[row][(g^(row&7))*8] = st3; }
                if (tid < TPF) sqP[tid] = sq_next;
            }
        }
        {
            int* dst = cand + ((size_t)b * NP + q0 + qsl) * CAND;
            dst[3 * sub + 0] = (int)(l0 & 0x7FFu);
            dst[3 * sub + 1] = (int)(l1 & 0x7FFu);
            dst[3 * sub + 2] = (int)(l2 & 0x7FFu);
        }
    } else if (bx < 1024) {
        // ===== vertex KNN — distributed top-24 (DPP) =====
        float* vx = (float*)smem;
        float* vy = (float*)(smem + 8192);
        float* vz = (float*)(smem + 16384);
        const int bb = bx - 512;
        const int b = bb >> 6, q0 = (bb & 63) * 32;
        const float* vb = vert + (size_t)b * NP * 3;

        for (int i = 0; i < NP * 3 / 256; ++i) {
            int e = i * 256 + tid;
            float v = vb[e];
            int row = e / 3, comp = e % 3;
            (comp == 0 ? vx : comp == 1 ? vy : vz)[row] = v;
        }
        __syncthreads();

        const int gbase = lane & 56;
        const int q = tid >> 3;
        const int sub = tid & 7;
        const float qx = vx[q0 + q], qy = vy[q0 + q], qz = vz[q0 + q];

        unsigned l0 = 0xFFFFFFFFu, l1 = 0xFFFFFFFFu, l2 = 0xFFFFFFFFu;
        unsigned T = 0xFFFFFFFFu;

        for (int m = 0; m < NP / 64; ++m) {
            const int p0 = m * 64 + sub * 8;
            float4 xA = *(const float4*)&vx[p0], xB = *(const float4*)&vx[p0 + 4];
            float4 yA = *(const float4*)&vy[p0], yB = *(const float4*)&vy[p0 + 4];
            float4 zA = *(const float4*)&vz[p0], zB = *(const float4*)&vz[p0 + 4];
            float dv[8];
            { float dx = qx-xA.x, dy = qy-yA.x, dz = qz-zA.x; dv[0] = dx*dx+dy*dy+dz*dz; }
            { float dx = qx-xA.y, dy = qy-yA.y, dz = qz-zA.y; dv[1] = dx*dx+dy*dy+dz*dz; }
            { float dx = qx-xA.z, dy = qy-yA.z, dz = qz-zA.z; dv[2] = dx*dx+dy*dy+dz*dz; }
            { float dx = qx-xA.w, dy = qy-yA.w, dz = qz-zA.w; dv[3] = dx*dx+dy*dy+dz*dz; }
            { float dx = qx-xB.x, dy = qy-yB.x, dz = qz-zB.x; dv[4] = dx*dx+dy*dy+dz*dz; }
            { float dx = qx-xB.y, dy = qy-yB.y, dz = qz-zB.y; dv[5] = dx*dx+dy*dy+dz*dz; }
            { float dx = qx-xB.z, dy = qy-yB.z, dz = qz-zB.z; dv[6] = dx*dx+dy*dy+dz*dz; }
            { float dx = qx-xB.w, dy = qy-yB.w, dz = qz-zB.w; dv[7] = dx*dx+dy*dy+dz*dz; }
            unsigned kv[8];
#pragma unroll
            for (int j = 0; j < 8; ++j) kv[j] = fkey(dv[j], p0 + j);
            if (m == 0) {
                unsigned m3 = third_smallest8(kv);
                m3 = umx(m3, (unsigned)__shfl_xor((int)m3, 1));
                m3 = umx(m3, (unsigned)__shfl_xor((int)m3, 2));
                m3 = umx(m3, (unsigned)__shfl_xor((int)m3, 4));
                T = m3 + 1;
            }
#pragma unroll
            for (int j = 0; j < 8; ++j) {
                unsigned long long bal = __ballot(kv[j] < T);
                unsigned gm = (unsigned)(bal >> gbase) & 0xFFu;
                while (gm) {
                    int l = __builtin_ctz(gm);
                    gm &= gm - 1;
                    unsigned k = (unsigned)__shfl((int)kv[j], gbase + l);
                    unsigned pv = dpp_prev(l2);
                    if (sub == 0) pv = 0u;
                    unsigned n0 = umn(umx(pv, k), l0);
                    unsigned n1 = umn(umx(l0, k), l1);
                    unsigned n2 = umn(umx(l1, k), l2);
                    l0 = n0; l1 = n1; l2 = n2;
                }
            }
            T = (unsigned)__shfl((int)l2, gbase + 7);
        }
        {
            int* dst = nbr2 + ((size_t)b * NP + q0 + q) * KNN;
            unsigned vals[3] = {l0, l1, l2};
#pragma unroll
            for (int e = 0; e < 3; ++e) {
                int r = 3 * sub + e;
                if (r >= 1 && r <= 16) dst[r - 1] = (int)(vals[e] & 0x7FFu);
            }
        }
    } else {
        // ===== fm GEMM — bf16 MFMA; center->fp32, support->bf16 =====
        short (*As)[128] = (short (*)[128])smem;
        const int bb = bx - 1024;
        const int m0 = (bb & 255) * 64, n0 = (bb >> 8) * 128;
        const int oct = lane >> 4;
        for (int i = 0; i < 4; ++i) {
            int v = i * 256 + tid, row = v >> 4, g = v & 15;
            *(bf16x8*)&As[row][(g ^ (row & 7)) * 8] =
                *(const bf16x8*)&fbb[(size_t)(m0 + row) * CIN + g * 8];
        }
        __syncthreads();
        f32x4 acc[4][2] = {};
#pragma unroll
        for (int kk = 0; kk < 4; ++kk) {
            int g = kk * 4 + oct;
            bf16x8 bv[2];
#pragma unroll
            for (int nt = 0; nt < 2; ++nt) {
                int n = n0 + (wid * 2 + nt) * 16 + (lane & 15);
                bv[nt] = *(const bf16x8*)&Wt[(size_t)n * CIN + g * 8];
            }
#pragma unroll
            for (int mt = 0; mt < 4; ++mt) {
                int ar = mt * 16 + (lane & 15);
                bf16x8 av = *(const bf16x8*)&As[ar][(g ^ (ar & 7)) * 8];
#pragma unroll
                for (int nt = 0; nt < 2; ++nt)
                    acc[mt][nt] = __builtin_amdgcn_mfma_f32_16x16x32_bf16(av, bv[nt], acc[mt][nt], 0, 0, 0);
            }
        }
#pragma unroll
        for (int mt = 0; mt < 4; ++mt)
#pragma unroll
            for (int nt = 0; nt < 2; ++nt) {
                int n = n0 + (wid * 2 + nt) * 16 + (lane & 15);
                float bsv = bias[n];
                int mbase = m0 + mt * 16 + oct * 4;
#pragma unroll
                for (int r = 0; r < 4; ++r) {
                    float val = acc[mt][nt][r] + bsv;
                    if (n0 == 0)
                        centerf[(size_t)(mbase + r) * OC + n] = val;
                    else
                        supb[(size_t)(mbase + r) * SC + (n - OC)] = (short)f2bf(val);
                }
            }
    }
}

// ---------- 2b: refine — 4-way parallel candidates, fp64 inner, REFERENCE fp32
// rounding chain preserved: d32 = fl32( fl32(sq_i)+fl32(sj) - fl32(2*dot) )
__global__ __launch_bounds__(256) void knn_refine_kernel(const float* __restrict__ feat,
                                                         const int* __restrict__ cand,
                                                         int* __restrict__ nbr) {
    __shared__ unsigned long long keyS[4][CAND];
    const int w = threadIdx.x >> 6;
    const int lane = threadIdx.x & 63;
    const int grp = lane >> 4, sl = lane & 15;
    const int gq = blockIdx.x * 4 + w;
    const int b = gq >> 11;
    const int q = gq & (NP - 1);
    const float* fb = feat + (size_t)b * NP * CIN;

    double qd[8];
    {
        float4 a = *(const float4*)&fb[(size_t)q * CIN + sl * 8];
        float4 c = *(const float4*)&fb[(size_t)q * CIN + sl * 8 + 4];
        qd[0] = a.x; qd[1] = a.y; qd[2] = a.z; qd[3] = a.w;
        qd[4] = c.x; qd[5] = c.y; qd[6] = c.z; qd[7] = c.w;
    }
    double sqd = 0.0;
#pragma unroll
    for (int i = 0; i < 8; ++i) sqd += qd[i] * qd[i];
#pragma unroll
    for (int msk = 1; msk <= 8; msk <<= 1) sqd += __shfl_xor(sqd, msk);
    const float sqi = (float)sqd;

    const int* cq = cand + (size_t)gq * CAND;
    int jv[CAND / 4];
#pragma unroll
    for (int t = 0; t < CAND / 4; ++t) jv[t] = cq[t * 4 + grp];

#pragma unroll
    for (int t = 0; t < CAND / 4; ++t) {
        const int j = jv[t];
        float4 a = *(const float4*)&fb[(size_t)j * CIN + sl * 8];
        float4 c = *(const float4*)&fb[(size_t)j * CIN + sl * 8 + 4];
        double fd[8] = {a.x, a.y, a.z, a.w, c.x, c.y, c.z, c.w};
        double dot = 0.0, sj = 0.0;
#pragma unroll
        for (int i = 0; i < 8; ++i) { dot += qd[i] * fd[i]; sj += fd[i] * fd[i]; }
#pragma unroll
        for (int msk = 1; msk <= 8; msk <<= 1) {
            dot += __shfl_xor(dot, msk);
            sj  += __shfl_xor(sj, msk);
        }
        if (sl == 0) {
            float t1 = sqi + (float)sj;
            float t2 = (float)(2.0 * dot);
            float d32 = t1 - t2;
            unsigned u = __float_as_uint(d32);
            u ^= (unsigned)((int)u >> 31) | 0x80000000u;
            keyS[w][t * 4 + grp] = ((unsigned long long)u << 32) | (unsigned)j;
        }
    }
    __syncthreads();
    if (lane < CAND) {
        unsigned long long k = keyS[w][lane];
        int rank = 0;
#pragma unroll
        for (int m = 0; m < CAND; ++m) rank += (keyS[w][m] < k) ? 1 : 0;
        if (rank < KNN) nbr[(size_t)gq * KNN + rank] = (int)(k & 0xFFFFFFFFu);
    }
}

// ---------- 5: activation — bf16 support gathers + center + bf16 copy ----------
__global__ __launch_bounds__(128) void act_kernel(const float* __restrict__ centerf,
                                                  const short* __restrict__ supb,
                                                  const int* __restrict__ nbr,
                                                  const float* __restrict__ vert,
                                                  const float4* __restrict__ sdnn4,
                                                  float* __restrict__ feature,
                                                  short* __restrict__ featb) {
    __shared__ int sj[KNN];
    __shared__ float rf[KNN][4];
    const int i = blockIdx.x;
    const int b = blockIdx.y;
    const int tid = threadIdx.x;
    const size_t bi = (size_t)b * NP + i;
    if (tid < KNN) {
        int j = nbr[bi * KNN + tid];
        sj[tid] = j;
        const float* vb = vert + (size_t)b * NP * 3;
        float dx = vb[j * 3 + 0] - vb[i * 3 + 0];
        float dy = vb[j * 3 + 1] - vb[i * 3 + 1];
        float dz = vb[j * 3 + 2] - vb[i * 3 + 2];
        float nrm = sqrtf(dx * dx + dy * dy + dz * dz);
        float den = fmaxf(nrm, 1e-12f);
        rf[tid][0] = dx / den; rf[tid][1] = dy / den; rf[tid][2] = dz / den;
    }
    __syncthreads();
    const int oc = tid;
    float accm = 0.0f;
#pragma unroll
    for (int s = 0; s < NSUP; ++s) {
        int m = s * OC + oc;
        float4 sv = sdnn4[m];
        float s0 = sv.x, s1 = sv.y, s2 = sv.z;
        float vm[4] = {-3.0e38f, -3.0e38f, -3.0e38f, -3.0e38f};
#pragma unroll
        for (int kk = 0; kk < KNN; ++kk) {
            float th = fmaxf(rf[kk][0] * s0 + rf[kk][1] * s1 + rf[kk][2] * s2, 0.0f);
            float sup = bf2f(supb[((size_t)b * NP + sj[kk]) * SC + m]);
            vm[kk & 3] = fmaxf(vm[kk & 3], th * sup);
        }
        accm += fmaxf(fmaxf(vm[0], vm[1]), fmaxf(vm[2], vm[3]));
    }
    float v = centerf[bi * OC + oc] + accm / 3.0f;
    feature[bi * OC + oc] = v;
    featb[bi * OC + oc] = (short)f2bf(v);
}

// ---------- 6: neighborhood max-pool (bf16 featb gathers) ----------
__global__ __launch_bounds__(128) void pool_kernel(const short* __restrict__ featb,
                                                   const int* __restrict__ nbr2,
                                                   float* __restrict__ pooled) {
    __shared__ int sj[KNN];
    const int i = blockIdx.x, b = blockIdx.y, tid = threadIdx.x;
    const size_t bi = (size_t)b * NP + i;
    if (tid < KNN) sj[tid] = nbr2[bi * KNN + tid];
    __syncthreads();
    float m0 = -3.0e38f, m1 = -3.0e38f, m2 = -3.0e38f, m3 = -3.0e38f;
#pragma unroll
    for (int kk = 0; kk < KNN; kk += 4) {
        m0 = fmaxf(m0, bf2f(featb[((size_t)b * NP + sj[kk + 0]) * OC + tid]));
        m1 = fmaxf(m1, bf2f(featb[((size_t)b * NP + sj[kk + 1]) * OC + tid]));
        m2 = fmaxf(m2, bf2f(featb[((size_t)b * NP + sj[kk + 2]) * OC + tid]));
        m3 = fmaxf(m3, bf2f(featb[((size_t)b * NP + sj[kk + 3]) * OC + tid]));
    }
    pooled[bi * OC + tid] = fmaxf(fmaxf(m0, m1), fmaxf(m2, m3));
}

// ---------- 7a: partial sums of pooled over N ----------
__global__ __launch_bounds__(128) void partial_kernel(const float* __restrict__ pooled,
                                                      float* __restrict__ part) {
    const int ch = blockIdx.x, b = blockIdx.y, tid = threadIdx.x;
    float s0 = 0.f, s1 = 0.f, s2 = 0.f, s3 = 0.f;
    const float* base = pooled + ((size_t)b * NP + ch * 128) * OC + tid;
    for (int i = 0; i < 128; i += 4) {
        s0 += base[(size_t)(i + 0) * OC];
        s1 += base[(size_t)(i + 1) * OC];
        s2 += base[(size_t)(i + 2) * OC];
        s3 += base[(size_t)(i + 3) * OC];
    }
    part[((size_t)b * 16 + ch) * OC + tid] = ((s0 + s1) + (s2 + s3));
}
// ---------- 7b: fused fglob + gdot ----------
__global__ __launch_bounds__(128) void fg_gdot_kernel(const float* __restrict__ part,
                                                      const float* __restrict__ conv2,
                                                      float* __restrict__ gd) {
    __shared__ float fgs[OC];
    const int b = blockIdx.x, tid = threadIdx.x;
    float s = 0.f;
#pragma unroll
    for (int c = 0; c < 16; ++c) s += part[((size_t)b * 16 + c) * OC + tid];
    fgs[tid] = s / (float)NP;
    __syncthreads();
    float g = 0.f;
    const float* w = conv2 + (size_t)tid * 2 * OC + OC;
    for (int c = 0; c < OC; ++c) g += fgs[c] * w[c];
    gd[b * OC + tid] = g;
}

// ---------- 8: final — bf16 MFMA conv2(feat) + ste(fmap) + gd + residual ----------
__global__ __launch_bounds__(256) void final_kernel(const short* __restrict__ featb,
                                                    const short* __restrict__ fbb,
                                                    const short* __restrict__ conv2b,
                                                    const short* __restrict__ stewb,
                                                    const float* __restrict__ gd,
                                                    const float* __restrict__ feature,
                                                    float* __restrict__ out) {
    __shared__ alignas(16) short Af[32][128];
    __shared__ alignas(16) short Am[32][128];
    const int m0 = blockIdx.x * 32, tid = threadIdx.x;
    const int lane = tid & 63, wid = tid >> 6, oct = lane >> 4;
    for (int i = 0; i < 2; ++i) {
        int v = i * 256 + tid, row = v >> 4, g = v & 15;
        *(bf16x8*)&Af[row][(g ^ (row & 7)) * 8] =
            *(const bf16x8*)&featb[(size_t)(m0 + row) * OC + g * 8];
        *(bf16x8*)&Am[row][(g ^ (row & 7)) * 8] =
            *(const bf16x8*)&fbb[(size_t)(m0 + row) * CIN + g * 8];
    }
    __syncthreads();
    f32x4 acc[2][2] = {};
#pragma unroll
    for (int kk = 0; kk < 4; ++kk) {
        int g = kk * 4 + oct;
        bf16x8 bC[2], bS[2];
#pragma unroll
        for (int nt = 0; nt < 2; ++nt) {
            int n = (wid * 2 + nt) * 16 + (lane & 15);
            bC[nt] = *(const bf16x8*)&conv2b[(size_t)n * (2 * OC) + g * 8];
            bS[nt] = *(const bf16x8*)&stewb[(size_t)n * CIN + g * 8];
        }
#pragma unroll
        for (int mt = 0; mt < 2; ++mt) {
            int ar = mt * 16 + (lane & 15);
            bf16x8 aF = *(const bf16x8*)&Af[ar][(g ^ (ar & 7)) * 8];
            bf16x8 aM = *(const bf16x8*)&Am[ar][(g ^ (ar & 7)) * 8];
#pragma unroll
            for (int nt = 0; nt < 2; ++nt) {
                acc[mt][nt] = __builtin_amdgcn_mfma_f32_16x16x32_bf16(aF, bC[nt], acc[mt][nt], 0, 0, 0);
                acc[mt][nt] = __builtin_amdgcn_mfma_f32_16x16x32_bf16(aM, bS[nt], acc[mt][nt], 0, 0, 0);
            }
        }
    }
#pragma unroll
    for (int mt = 0; mt < 2; ++mt)
#pragma unroll
        for (int nt = 0; nt < 2; ++nt) {
            int o = (wid * 2 + nt) * 16 + (lane & 15);
            int mbase = m0 + mt * 16 + oct * 4;
#pragma unroll
            for (int r = 0; r < 4; ++r) {
                int m = mbase + r;
                out[(size_t)m * OC + o] = acc[mt][nt][r]
                    + gd[(m >> 11) * OC + o] + feature[(size_t)m * OC + o];
            }
        }
}

extern "C" void kernel_launch(void* const* d_in, const int* in_sizes, int n_in,
                              void* d_out, int out_size, void* d_ws, size_t ws_size,
                              hipStream_t stream) {
    const float* vert  = (const float*)d_in[0];
    const float* fmap  = (const float*)d_in[1];
    const float* W     = (const float*)d_in[2];
    const float* bias  = (const float*)d_in[3];
    const float* dirs  = (const float*)d_in[4];
    const float* stew  = (const float*)d_in[5];
    const float* conv2 = (const float*)d_in[6];
    float* out = (float*)d_out;

    float* ws      = (float*)d_ws;
    float* sqn     = ws;                             // 16384
    short* fbb     = (short*)(sqn + 16384);          // 2M shorts
    float* centerf = sqn + 16384 + 1048576;          // 2M floats
    short* supb    = (short*)(centerf + 2097152);    // 6.29M shorts
    float* feature = centerf + 2097152 + 3145728;    // 2M floats
    short* featb   = (short*)(feature + 2097152);    // 2M shorts
    float* gd      = feature + 2097152 + 1048576;    // 1024
    short* Wt      = (short*)(gd + 1024);            // 65536 shorts
    short* conv2b  = Wt + 65536;                     // 32768 shorts
    short* stewb   = conv2b + 32768;                 // 16384 shorts
    int*   nbr1    = (int*)(stewb + 16384);          // 262144
    int*   nbr2    = nbr1 + 262144;                  // 262144
    float* part    = (float*)(nbr2 + 262144);        // 16384
    float4* sdnn4  = (float4*)(part + 16384);        // 384 float4
    int*   cand    = (int*)(sdnn4 + 384);            // 393216
    float* pooled  = (float*)(cand + 393216);        // 2M floats

    prep_kernel<<<1474, 256, 0, stream>>>(fmap, sqn, fbb, W, conv2, stew, dirs,
                                          Wt, conv2b, stewb, sdnn4);
    fused_kernel<<<2048, 256, 0, stream>>>(fbb, sqn, cand, vert, nbr2,
                                           Wt, bias, centerf, supb);
    knn_refine_kernel<<<4096, 256, 0, stream>>>(fmap, cand, nbr1);
    act_kernel<<<dim3(2048, 8), 128, 0, stream>>>(centerf, supb, nbr1, vert, sdnn4,
                                                  feature, featb);
    pool_kernel<<<dim3(2048, 8), 128, 0, stream>>>(featb, nbr2, pooled);
    partial_kernel<<<dim3(16, 8), 128, 0, stream>>>(pooled, part);
    fg_gdot_kernel<<<8, 128, 0, stream>>>(part, conv2, gd);
    final_kernel<<<512, 256, 0, stream>>>(featb, fbb, conv2b, stewb, gd, feature, out);
}